// Round 3
// baseline (48.297 us; speedup 1.0000x reference)
//
#include <hip/hip_runtime.h>

// Delay-logistic DDE, forward Euler, d independent scalar components.
// x_{i+1} = x_i * m_i,  m_i = (1+a) - a*th1*y_i,  a = dt*th0,
// y_i = x_{i-100} (constant history x_0 for i < 100).
// Output: out[j*(N+1) + t] = x_t  (row-major [d, N+1]).
//
// Block = (64-component chunk) x (time-group g). Recompute groups 0..g from
// x_0 (serial chain <= 1000 multiplies), then emit group g's 100 columns via
// FIVE 20-column LDS transposes (5.25 KB LDS -> 16 waves/CU, vs 6 with the
// full 25.9 KB tile). Single-wave blocks + in-order DS pipe => NO barriers,
// so no forced vmcnt(0) drains; stores pipeline across phases.

constexpr int NT   = 1000;          // N steps (setup_inputs: N=1000)
constexpr int NTAU = 100;           // steps per delay interval
constexpr int NGRP = NT / NTAU;     // 10 groups
constexpr int NP1  = NT + 1;        // 1001 columns per row
constexpr int CPB  = 64;            // components per block == block size (1 wave)
constexpr int TPH  = 20;            // time-columns per staging phase
constexpr int NPH  = NTAU / TPH;    // 5 phases
constexpr int LSTR = TPH + 1;       // 21 dwords: gcd(21,32)=1 -> conflict-free
constexpr int RPI  = 3;             // rows per store instr (3*20 = 60 lanes)
constexpr int NSI  = (CPB + RPI - 1) / RPI;  // 22 store instrs per phase

__global__ __launch_bounds__(CPB, 4)   // cap 128 VGPR -> 16 waves/CU
void ndde_kernel(const float* __restrict__ x0,
                 const float* __restrict__ tau,
                 const float* __restrict__ params,
                 float* __restrict__ out)
{
    __shared__ float lds[CPB][LSTR];
    const int tid = threadIdx.x;
    // g = NGRP-1 - blockIdx.y: longest-recompute blocks dispatch FIRST.
    const int g = (NGRP - 1) - (int)blockIdx.y;
    const long long jbase = (long long)blockIdx.x * CPB;

    const float dt = 0.01f * tau[0];
    const float a  = dt * params[0];        // dt * theta0
    const float q  = -(a * params[1]);      // -dt*theta0*theta1
    const float p  = 1.0f + a;

    float x = x0[jbase + tid];
    // h[k] at start of group gg holds x_{100*(gg-1)+k}; constant history gg=0.
    float h[NTAU];
#pragma unroll
    for (int k = 0; k < NTAU; ++k) h[k] = x;

    // Recompute groups 0..g; after iteration gg, h[k] = x_{100*gg+k}.
    for (int gg = 0; gg <= g; ++gg) {
#pragma unroll
        for (int k = 0; k < NTAU; ++k) {
            const float y = h[k];           // x_{i-100}
            const float m = fmaf(q, y, p);  // (1+a) - a*th1*y
            h[k] = x;                       // becomes x_{100*gg+k}
            x *= m;
        }
    }
    // h[k] = x_{100g+k}: output columns t = 100g .. 100g+99.

    // Drain lane mapping: lane = (row-offset lq, time lt) within a phase.
    const int lq = tid / TPH;               // 0..3 (lq==3 -> inactive)
    const int lt = tid - lq * TPH;          // 0..19
    const long long colbase = (long long)g * NTAU;

    for (int c = 0; c < NPH; ++c) {
        // Stage 20 columns: lane tid writes its row (stride 21 -> no conflict).
#pragma unroll
        for (int k = 0; k < TPH; ++k) lds[tid][k] = h[c * TPH + k];
        // No barrier: single wave, DS pipe is in-order per wave.

        // Dense transpose drain: instr i covers rows 3i..3i+2, cols lt.
        const float* lrow = &lds[lq][lt];   // + i*3*LSTR dwords per instr
        float* gp = out + (jbase + lq) * NP1 + colbase + c * TPH + lt;
#pragma unroll
        for (int i = 0; i < NSI; ++i) {
            const int r = RPI * i + lq;
            if (lq < RPI && r < CPB)
                gp[(long long)RPI * i * NP1] = lrow[RPI * i * LSTR];
        }
    }

    // Final column t = N written by the g = NGRP-1 blocks (x = x_1000 here).
    if (g == NGRP - 1)
        out[(jbase + tid) * NP1 + NT] = x;
}

extern "C" void kernel_launch(void* const* d_in, const int* in_sizes, int n_in,
                              void* d_out, int out_size, void* d_ws, size_t ws_size,
                              hipStream_t stream) {
    const float* x0     = (const float*)d_in[0];
    const float* tau    = (const float*)d_in[1];
    const float* params = (const float*)d_in[2];
    float* out = (float*)d_out;
    const int d = in_sizes[0];              // 32768
    const int chunks = d / CPB;             // 512
    dim3 grid(chunks, NGRP);
    ndde_kernel<<<grid, CPB, 0, stream>>>(x0, tau, params, out);
}